// Round 1
// 240.048 us; speedup vs baseline: 1.0189x; 1.0189x over previous
//
#include <hip/hip_runtime.h>

#define B_ 2
#define N_ 2048
#define F_ 64
#define C_ 64
#define L_ 4
#define SK 4    // split-K factor over j: 4 blocks/CU for latency decorrelation
#define NJ (N_ / SK)        // 512 j per block
#define TSTEPS (NJ / 32)    // 16 K-steps
#define PJ 40   // padded LDS j-stride (halves): 80 B rows -> 16B-aligned b128 reads, ~2-way banks

typedef _Float16 half8 __attribute__((ext_vector_type(8)));
typedef _Float16 half2 __attribute__((ext_vector_type(2)));
typedef float floatx4 __attribute__((ext_vector_type(4)));

// ---------------------------------------------------------------------------
// K0: V[b][j][f] -> Vth[b][f][j] (fp16), LDS transpose.  (unchanged)
// grid = B * N/64 = 64 blocks, 256 threads
// ---------------------------------------------------------------------------
__global__ __launch_bounds__(256) void k0_transpose(const float* __restrict__ V,
                                                    _Float16* __restrict__ Vth) {
    __shared__ float tile[64][65];
    const int b  = blockIdx.x >> 5;          // 0..1
    const int j0 = (blockIdx.x & 31) * 64;   // j tile base
    const int tid = threadIdx.x;

    const floatx4* V4 = (const floatx4*)(V + ((size_t)(b * N_ + j0)) * F_);
#pragma unroll
    for (int s = 0; s < 4; ++s) {
        int g = tid + 256 * s;               // 0..1023 float4 slots
        int jl = g >> 4;                     // 0..63
        int fq = g & 15;                     // 0..15
        floatx4 v = V4[jl * 16 + fq];
        tile[jl][fq * 4 + 0] = v.x;
        tile[jl][fq * 4 + 1] = v.y;
        tile[jl][fq * 4 + 2] = v.z;
        tile[jl][fq * 4 + 3] = v.w;
    }
    __syncthreads();

    const int f = tid >> 2;                  // 0..63
    const int jb = (tid & 3) * 16;           // 0..48
    _Float16* dh = Vth + ((size_t)(b * F_ + f)) * N_ + j0 + jb;
#pragma unroll
    for (int u = 0; u < 16; u += 4) {
        half2 h01 = {(_Float16)tile[jb + u + 0][f], (_Float16)tile[jb + u + 1][f]};   // RNE
        half2 h23 = {(_Float16)tile[jb + u + 2][f], (_Float16)tile[jb + u + 3][f]};
        *(half2*)(dh + u + 0) = h01;
        *(half2*)(dh + u + 2) = h23;
    }
}

// ---------------------------------------------------------------------------
// K1: fused deg + agg via fp16 MFMA, split-K over j.
// grid = B * N/16 * SK = 1024 blocks (4/CU), 256 thr (4 waves).
//
// ROUND CHANGE 1: __syncthreads() -> lgkmcnt-only barrier.  __syncthreads
// lowers to "s_waitcnt vmcnt(0) lgkmcnt(0); s_barrier", which drains the
// depth-2 A/V global prefetch at EVERY 32-j step (16x per block) and exposes
// full HBM latency each iteration.  The barrier only orders the LDS
// double-buffer; global-load consumption is already ordered by the
// compiler's own register-dependency waitcnts one iteration later.  So wait
// on lgkmcnt(0) only (our ds_writes) and issue a raw s_barrier.  The
// sched_barrier(0) fences pin memory ops on their side of the barrier.
//
// ROUND CHANGE 2: aggT layout [p][b][k][i] -> [p][b][i>>2][k][i&3] so K2's
// partial-sum read is contiguous (1 KB/instr) instead of a 64-line gather.
// Epilogue stores become 4x256B segments per instr (fully dense lines).
// ---------------------------------------------------------------------------
__global__ __launch_bounds__(256, 4) void k1_agg(const float* __restrict__ A,
                                                 const _Float16* __restrict__ Vth,
                                                 float* __restrict__ aggT,
                                                 float* __restrict__ degT) {
    __shared__ _Float16 lds[2 * 4 * 16 * PJ];   // 10 KB: [buf][l][i][PJ]

    const int bid = blockIdx.x;          // 0..1023
    const int b   = bid >> 9;
    const int rem = bid & 511;
    const int i0  = (rem >> 2) * 16;
    const int p   = rem & 3;             // split-K slice
    const int tid  = threadIdx.x;
    const int w    = tid >> 6;       // wave id == l
    const int lane = tid & 63;
    const int m    = lane & 15;      // A row / B col / C col within tile
    const int q    = lane >> 4;      // quad group

    // staging mapping: thread -> (row i_s, j-pair jp)
    const int i_s = tid >> 4;        // 0..15
    const int jp  = tid & 15;        // 0..15 -> j = 2jp, 2jp+1

    const floatx4* Abase = (const floatx4*)A + ((size_t)(b * N_ + i0 + i_s)) * N_ + p * NJ;
    const _Float16* Vrow = Vth + ((size_t)b * F_) * N_ + p * NJ;

    floatx4 acc0 = {0,0,0,0}, acc1 = {0,0,0,0}, acc2 = {0,0,0,0}, acc3 = {0,0,0,0};
    floatx4 accd = {0,0,0,0};

    half8 bones;                     // B[k][0] = 1 -> col 0 of deg tile = row sums
#pragma unroll
    for (int e = 0; e < 8; ++e) bones[e] = (m == 0) ? (_Float16)1.0f : (_Float16)0.0f;

    floatx4 a_cur0, a_cur1, a_nxt0, a_nxt1;
    half8 v_cur0, v_cur1, v_cur2, v_cur3, v_nxt0, v_nxt1, v_nxt2, v_nxt3;

#define LOAD_A(t, x0, x1) do { int jj = (t) * 32 + 2 * jp; x0 = Abase[jj]; x1 = Abase[jj + 1]; } while (0)
#define LOAD_V(t, v0, v1, v2, v3) do { int jj = (t) * 32 + q * 8;                                  \
        v0 = *(const half8*)(Vrow + (size_t)(0  + m) * N_ + jj);                                   \
        v1 = *(const half8*)(Vrow + (size_t)(16 + m) * N_ + jj);                                   \
        v2 = *(const half8*)(Vrow + (size_t)(32 + m) * N_ + jj);                                   \
        v3 = *(const half8*)(Vrow + (size_t)(48 + m) * N_ + jj); } while (0)

    LOAD_A(0, a_cur0, a_cur1);
    LOAD_V(0, v_cur0, v_cur1, v_cur2, v_cur3);
    LOAD_A(1, a_nxt0, a_nxt1);
    LOAD_V(1, v_nxt0, v_nxt1, v_nxt2, v_nxt3);

#pragma unroll 2
    for (int t = 0; t < TSTEPS; ++t) {
        const int buf = t & 1;
        _Float16* dst = lds + buf * (4 * 16 * PJ);
        {   // fp32 -> fp16 (RNE) + LDS write: lane holds A[i_s][2jp..2jp+1][l=0..3]
            const float* c0 = (const float*)&a_cur0;
            const float* c1 = (const float*)&a_cur1;
#pragma unroll
            for (int l = 0; l < 4; ++l) {
                half2 h = {(_Float16)c0[l], (_Float16)c1[l]};
                *(half2*)(dst + (l * 16 + i_s) * PJ + 2 * jp) = h;
            }
        }
        // lgkmcnt-only barrier: do NOT drain vmcnt (keeps A/V prefetch in flight)
        __builtin_amdgcn_sched_barrier(0);
        asm volatile("s_waitcnt lgkmcnt(0)" ::: "memory");
        __builtin_amdgcn_s_barrier();
        __builtin_amdgcn_sched_barrier(0);

        // rotate prefetch (depth 2: tile t+2 issued now, consumed at iter t+2)
        a_cur0 = a_nxt0; a_cur1 = a_nxt1;
        const int tn = (t + 2 < TSTEPS) ? (t + 2) : (TSTEPS - 1);
        LOAD_A(tn, a_nxt0, a_nxt1);

        // compute: A-frag from LDS plane l=w, B-frags from registers
        half8 af = *(const half8*)(lds + buf * (4 * 16 * PJ) + (w * 16 + m) * PJ + q * 8);
        acc0 = __builtin_amdgcn_mfma_f32_16x16x32_f16(af, v_cur0, acc0, 0, 0, 0);
        acc1 = __builtin_amdgcn_mfma_f32_16x16x32_f16(af, v_cur1, acc1, 0, 0, 0);
        acc2 = __builtin_amdgcn_mfma_f32_16x16x32_f16(af, v_cur2, acc2, 0, 0, 0);
        acc3 = __builtin_amdgcn_mfma_f32_16x16x32_f16(af, v_cur3, acc3, 0, 0, 0);
        accd = __builtin_amdgcn_mfma_f32_16x16x32_f16(af, bones,  accd, 0, 0, 0);

        v_cur0 = v_nxt0; v_cur1 = v_nxt1; v_cur2 = v_nxt2; v_cur3 = v_nxt3;
        LOAD_V(tn, v_nxt0, v_nxt1, v_nxt2, v_nxt3);
    }
#undef LOAD_A
#undef LOAD_V

    // epilogue: C layout col=lane&15 (f->k), row=q*4+reg (i).
    // NEW layout: aggT[p][b][it = i>>2][k][i&3]; acc float4 = 4 consecutive i
    // = exactly (it = i0/4 + q, r=0..3).  Store = rowp + k*4, 16 lanes (m)
    // contiguous 256 B, 4 q-segments at 4 KB stride.
    float* aggb = aggT + ((size_t)(p * B_ + b)) * (512 * 1024);   // 2 MB per (p,b)
    float* rowp = aggb + ((size_t)((i0 >> 2) + q)) * 1024;
    *(floatx4*)(rowp + (w * 64 +  0 + m) * 4) = acc0;
    *(floatx4*)(rowp + (w * 64 + 16 + m) * 4) = acc1;
    *(floatx4*)(rowp + (w * 64 + 32 + m) * 4) = acc2;
    *(floatx4*)(rowp + (w * 64 + 48 + m) * 4) = acc3;
    if (m == 0) {
        const int ibase = i0 + q * 4;
        *(floatx4*)(degT + ((size_t)((p * B_ + b) * L_ + w)) * N_ + ibase) = accd;
    }
}

// ---------------------------------------------------------------------------
// K2: out[b,i,c] = sigmoid(V@w1 + (deg (x) V)@w2 - agg@w3), fp32 VALU.
// grid = B * N/4 = 1024 blocks (4/CU, 16 waves/CU), 256 thr.
// Phase 1a now reads the permuted aggT layout: lane k reads a contiguous
// 16 B float4 (i0..i0+3 for its k), wave = 1 KB dense per instruction.
// ---------------------------------------------------------------------------
__global__ __launch_bounds__(256) void k2_out(const float* __restrict__ V,
                                              const float* __restrict__ degT,
                                              const float* __restrict__ aggT,
                                              const float* __restrict__ w1,
                                              const float* __restrict__ w2,
                                              const float* __restrict__ w3,
                                              float* __restrict__ out) {
    __shared__ float xsum[256][4];   // [k][i_loc]  summed agg partials
    __shared__ float vt[4][64];      // [i_loc][f]
    __shared__ float dsum[4][4];     // [l][i_loc]  summed deg partials

    const int raw = blockIdx.x;      // 0..1023
    const int b   = raw >> 9;
    const int t9  = raw & 511;
    // XCD swizzle retained (harmless; decorrelates block start times per XCD)
    const int tile = ((t9 & 7) << 6) | (t9 >> 3);
    const int i0  = tile * 4;
    const int tid = threadIdx.x;

    // phase 1a: xsum[k][0..3] = sum_p aggT[p][b][tile][k][0..3]  (contiguous!)
    {
        const int k = tid;
        const float* g = aggT + (size_t)b * (512 * 1024) + (size_t)tile * 1024 + (size_t)k * 4;
        const size_t PS = (size_t)B_ * 512 * 1024;
        floatx4 s = *(const floatx4*)(g);
        s += *(const floatx4*)(g + PS);
        s += *(const floatx4*)(g + 2 * PS);
        s += *(const floatx4*)(g + 3 * PS);
        *(floatx4*)&xsum[k][0] = s;
    }
    // phase 1b: vt[i_loc][f] (coalesced 1 KB)
    {
        const int il = tid >> 6, f = tid & 63;
        vt[il][f] = V[((size_t)(b * N_ + i0 + il)) * F_ + f];
    }
    // phase 1c: dsum[l][i_loc]
    if (tid < 16) {
        const int l = tid >> 2, il = tid & 3;
        float s = 0.0f;
#pragma unroll
        for (int p = 0; p < SK; ++p)
            s += degT[((size_t)((p * B_ + b) * L_ + l)) * N_ + i0 + il];
        dsum[l][il] = s;
    }
    __syncthreads();

    // phase 2: one thread per (i_loc, c); wave = one i row (LDS reads broadcast)
    const int il = tid >> 6;
    const int c  = tid & 63;
    const float d0 = dsum[0][il], d1 = dsum[1][il], d2 = dsum[2][il], d3 = dsum[3][il];

    float acc = 0.0f;
#pragma unroll 4
    for (int f = 0; f < 64; ++f) {
        const float x = vt[il][f];
        acc += x        * w1[f * 64 + c];
        acc += (d0 * x) * w2[(0 * 64 + f) * 64 + c];
        acc += (d1 * x) * w2[(1 * 64 + f) * 64 + c];
        acc += (d2 * x) * w2[(2 * 64 + f) * 64 + c];
        acc += (d3 * x) * w2[(3 * 64 + f) * 64 + c];
    }
#pragma unroll 4
    for (int k = 0; k < 256; ++k) {
        acc -= xsum[k][il] * w3[k * 64 + c];
    }

    out[((size_t)(b * N_ + i0 + il)) * C_ + c] = 1.0f / (1.0f + __expf(-acc));
}

// ---------------------------------------------------------------------------
extern "C" void kernel_launch(void* const* d_in, const int* in_sizes, int n_in,
                              void* d_out, int out_size, void* d_ws, size_t ws_size,
                              hipStream_t stream) {
    const float* V  = (const float*)d_in[0];
    const float* A  = (const float*)d_in[1];
    const float* w1 = (const float*)d_in[2];
    const float* w2 = (const float*)d_in[3];
    const float* w3 = (const float*)d_in[4];
    float* out = (float*)d_out;

    char* ws = (char*)d_ws;
    float*    aggT = (float*)(ws);                  // SK*B*512*1024*4 = 16 MB (permuted layout)
    float*    degT = (float*)(ws + 16777216);       // SK*B*L*N*4   = 256 KB
    _Float16* Vth  = (_Float16*)(ws + 17039360);    // B*F*N*2      = 512 KB

    hipLaunchKernelGGL(k0_transpose, dim3(B_ * (N_ / 64)), dim3(256), 0, stream, V, Vth);
    hipLaunchKernelGGL(k1_agg,       dim3(B_ * (N_ / 16) * SK), dim3(256), 0, stream,
                       A, Vth, aggT, degT);
    hipLaunchKernelGGL(k2_out,       dim3(B_ * (N_ / 4)), dim3(256), 0, stream,
                       V, degT, aggT, w1, w2, w3, out);
}

// Round 2
// 217.069 us; speedup vs baseline: 1.1267x; 1.1059x over previous
//
#include <hip/hip_runtime.h>

#define B_ 2
#define N_ 2048
#define F_ 64
#define C_ 64
#define L_ 4
#define SK 4    // split-K factor over j: 4 blocks/CU for latency decorrelation
#define NJ (N_ / SK)        // 512 j per block
#define TSTEPS (NJ / 32)    // 16 K-steps
#define PJ 40   // padded LDS j-stride (halves): 80 B rows -> 16B-aligned b128 reads, ~2-way banks

typedef _Float16 half8 __attribute__((ext_vector_type(8)));
typedef _Float16 half2 __attribute__((ext_vector_type(2)));
typedef float floatx4 __attribute__((ext_vector_type(4)));

// ---------------------------------------------------------------------------
// K0: V[b][j][f] -> Vth[b][f][j] (fp16), LDS transpose.  (unchanged, verified)
// grid = B * N/64 = 64 blocks, 256 threads
// ---------------------------------------------------------------------------
__global__ __launch_bounds__(256) void k0_transpose(const float* __restrict__ V,
                                                    _Float16* __restrict__ Vth) {
    __shared__ float tile[64][65];
    const int b  = blockIdx.x >> 5;          // 0..1
    const int j0 = (blockIdx.x & 31) * 64;   // j tile base
    const int tid = threadIdx.x;

    const floatx4* V4 = (const floatx4*)(V + ((size_t)(b * N_ + j0)) * F_);
#pragma unroll
    for (int s = 0; s < 4; ++s) {
        int g = tid + 256 * s;               // 0..1023 float4 slots
        int jl = g >> 4;                     // 0..63
        int fq = g & 15;                     // 0..15
        floatx4 v = V4[jl * 16 + fq];
        tile[jl][fq * 4 + 0] = v.x;
        tile[jl][fq * 4 + 1] = v.y;
        tile[jl][fq * 4 + 2] = v.z;
        tile[jl][fq * 4 + 3] = v.w;
    }
    __syncthreads();

    const int f = tid >> 2;                  // 0..63
    const int jb = (tid & 3) * 16;           // 0..48
    _Float16* dh = Vth + ((size_t)(b * F_ + f)) * N_ + j0 + jb;
#pragma unroll
    for (int u = 0; u < 16; u += 4) {
        half2 h01 = {(_Float16)tile[jb + u + 0][f], (_Float16)tile[jb + u + 1][f]};   // RNE
        half2 h23 = {(_Float16)tile[jb + u + 2][f], (_Float16)tile[jb + u + 3][f]};
        *(half2*)(dh + u + 0) = h01;
        *(half2*)(dh + u + 2) = h23;
    }
}

// ---------------------------------------------------------------------------
// K1: fused deg + agg via fp16 MFMA, split-K over j.  (unchanged from round 1,
// verified.  Round-1 post-mortem: main loop is BW-bound at ~22-25 us already
// — per-CU in-flight A bytes (~65 KB) exceed the Little's-law requirement
// (~9 KB) by 7x, so the lgkm-only barrier was neutral; keep it, it's free.)
// grid = B * N/16 * SK = 1024 blocks (4/CU), 256 thr (4 waves).
// aggT layout [p][b][i>>2][k][i&3] (round-1 change, verified: K2 reads dense).
// ---------------------------------------------------------------------------
__global__ __launch_bounds__(256, 4) void k1_agg(const float* __restrict__ A,
                                                 const _Float16* __restrict__ Vth,
                                                 float* __restrict__ aggT,
                                                 float* __restrict__ degT) {
    __shared__ _Float16 lds[2 * 4 * 16 * PJ];   // 10 KB: [buf][l][i][PJ]

    const int bid = blockIdx.x;          // 0..1023
    const int b   = bid >> 9;
    const int rem = bid & 511;
    const int i0  = (rem >> 2) * 16;
    const int p   = rem & 3;             // split-K slice
    const int tid  = threadIdx.x;
    const int w    = tid >> 6;       // wave id == l
    const int lane = tid & 63;
    const int m    = lane & 15;      // A row / B col / C col within tile
    const int q    = lane >> 4;      // quad group

    // staging mapping: thread -> (row i_s, j-pair jp)
    const int i_s = tid >> 4;        // 0..15
    const int jp  = tid & 15;        // 0..15 -> j = 2jp, 2jp+1

    const floatx4* Abase = (const floatx4*)A + ((size_t)(b * N_ + i0 + i_s)) * N_ + p * NJ;
    const _Float16* Vrow = Vth + ((size_t)b * F_) * N_ + p * NJ;

    floatx4 acc0 = {0,0,0,0}, acc1 = {0,0,0,0}, acc2 = {0,0,0,0}, acc3 = {0,0,0,0};
    floatx4 accd = {0,0,0,0};

    half8 bones;                     // B[k][0] = 1 -> col 0 of deg tile = row sums
#pragma unroll
    for (int e = 0; e < 8; ++e) bones[e] = (m == 0) ? (_Float16)1.0f : (_Float16)0.0f;

    floatx4 a_cur0, a_cur1, a_nxt0, a_nxt1;
    half8 v_cur0, v_cur1, v_cur2, v_cur3, v_nxt0, v_nxt1, v_nxt2, v_nxt3;

#define LOAD_A(t, x0, x1) do { int jj = (t) * 32 + 2 * jp; x0 = Abase[jj]; x1 = Abase[jj + 1]; } while (0)
#define LOAD_V(t, v0, v1, v2, v3) do { int jj = (t) * 32 + q * 8;                                  \
        v0 = *(const half8*)(Vrow + (size_t)(0  + m) * N_ + jj);                                   \
        v1 = *(const half8*)(Vrow + (size_t)(16 + m) * N_ + jj);                                   \
        v2 = *(const half8*)(Vrow + (size_t)(32 + m) * N_ + jj);                                   \
        v3 = *(const half8*)(Vrow + (size_t)(48 + m) * N_ + jj); } while (0)

    LOAD_A(0, a_cur0, a_cur1);
    LOAD_V(0, v_cur0, v_cur1, v_cur2, v_cur3);
    LOAD_A(1, a_nxt0, a_nxt1);
    LOAD_V(1, v_nxt0, v_nxt1, v_nxt2, v_nxt3);

#pragma unroll 2
    for (int t = 0; t < TSTEPS; ++t) {
        const int buf = t & 1;
        _Float16* dst = lds + buf * (4 * 16 * PJ);
        {   // fp32 -> fp16 (RNE) + LDS write: lane holds A[i_s][2jp..2jp+1][l=0..3]
            const float* c0 = (const float*)&a_cur0;
            const float* c1 = (const float*)&a_cur1;
#pragma unroll
            for (int l = 0; l < 4; ++l) {
                half2 h = {(_Float16)c0[l], (_Float16)c1[l]};
                *(half2*)(dst + (l * 16 + i_s) * PJ + 2 * jp) = h;
            }
        }
        // lgkmcnt-only barrier: do NOT drain vmcnt (keeps A/V prefetch in flight)
        __builtin_amdgcn_sched_barrier(0);
        asm volatile("s_waitcnt lgkmcnt(0)" ::: "memory");
        __builtin_amdgcn_s_barrier();
        __builtin_amdgcn_sched_barrier(0);

        // rotate prefetch (depth 2: tile t+2 issued now, consumed at iter t+2)
        a_cur0 = a_nxt0; a_cur1 = a_nxt1;
        const int tn = (t + 2 < TSTEPS) ? (t + 2) : (TSTEPS - 1);
        LOAD_A(tn, a_nxt0, a_nxt1);

        // compute: A-frag from LDS plane l=w, B-frags from registers
        half8 af = *(const half8*)(lds + buf * (4 * 16 * PJ) + (w * 16 + m) * PJ + q * 8);
        acc0 = __builtin_amdgcn_mfma_f32_16x16x32_f16(af, v_cur0, acc0, 0, 0, 0);
        acc1 = __builtin_amdgcn_mfma_f32_16x16x32_f16(af, v_cur1, acc1, 0, 0, 0);
        acc2 = __builtin_amdgcn_mfma_f32_16x16x32_f16(af, v_cur2, acc2, 0, 0, 0);
        acc3 = __builtin_amdgcn_mfma_f32_16x16x32_f16(af, v_cur3, acc3, 0, 0, 0);
        accd = __builtin_amdgcn_mfma_f32_16x16x32_f16(af, bones,  accd, 0, 0, 0);

        v_cur0 = v_nxt0; v_cur1 = v_nxt1; v_cur2 = v_nxt2; v_cur3 = v_nxt3;
        LOAD_V(tn, v_nxt0, v_nxt1, v_nxt2, v_nxt3);
    }
#undef LOAD_A
#undef LOAD_V

    // epilogue: C layout col=lane&15 (f->k), row=q*4+reg (i).
    // aggT[p][b][it = i>>2][k][i&3]; 16 lanes (m) contiguous 256 B per store.
    float* aggb = aggT + ((size_t)(p * B_ + b)) * (512 * 1024);   // 2 MB per (p,b)
    float* rowp = aggb + ((size_t)((i0 >> 2) + q)) * 1024;
    *(floatx4*)(rowp + (w * 64 +  0 + m) * 4) = acc0;
    *(floatx4*)(rowp + (w * 64 + 16 + m) * 4) = acc1;
    *(floatx4*)(rowp + (w * 64 + 32 + m) * 4) = acc2;
    *(floatx4*)(rowp + (w * 64 + 48 + m) * 4) = acc3;
    if (m == 0) {
        const int ibase = i0 + q * 4;
        *(floatx4*)(degT + ((size_t)((p * B_ + b) * L_ + w)) * N_ + ibase) = accd;
    }
}

// ---------------------------------------------------------------------------
// K2: out[b,i,c] = sigmoid(V@w1 + (deg (x) V)@w2 - agg@w3), fp32 VALU.
// grid = B * N/4 = 1024 blocks (4/CU, 16 waves/CU), 256 thr.
//
// ROUND CHANGE: phase 2 was issuing 576 scalar global weight loads PER THREAD
// (all 4 waves re-streaming identical w1/w2/w3 for their own i-row) — a pure
// load-issue bottleneck (~16 waves/CU x 576 wave-loads through L1 ≈ 15-20 us),
// not BW (weights are L2-resident).  New scheme: wave w owns f-quarter
// [16w,16w+16) and k-quarter [64w,64w+64) and computes partials for ALL 4
// i-rows, reusing every weight load 4x (576 -> 144 loads/thread).  xsum[k][*]
// becomes one ds_read_b128 broadcast.  Cross-wave reduce via 4 KB LDS.
// ---------------------------------------------------------------------------
__global__ __launch_bounds__(256) void k2_out(const float* __restrict__ V,
                                              const float* __restrict__ degT,
                                              const float* __restrict__ aggT,
                                              const float* __restrict__ w1,
                                              const float* __restrict__ w2,
                                              const float* __restrict__ w3,
                                              float* __restrict__ out) {
    __shared__ float xsum[256][4];   // [k][i_loc]  summed agg partials
    __shared__ float vt[4][64];      // [i_loc][f]
    __shared__ float dsum[4][4];     // [l][i_loc]  summed deg partials
    __shared__ float red[4][4][64];  // [wave][i_loc][c] partial outputs

    const int raw = blockIdx.x;      // 0..1023
    const int b   = raw >> 9;
    const int t9  = raw & 511;
    // XCD swizzle: consecutive-i tiles land on the same XCD (bijection)
    const int tile = ((t9 & 7) << 6) | (t9 >> 3);
    const int i0  = tile * 4;
    const int tid = threadIdx.x;

    // phase 1a: xsum[k][0..3] = sum_p aggT[p][b][tile][k][0..3]  (contiguous)
    {
        const int k = tid;
        const float* g = aggT + (size_t)b * (512 * 1024) + (size_t)tile * 1024 + (size_t)k * 4;
        const size_t PS = (size_t)B_ * 512 * 1024;
        floatx4 s = *(const floatx4*)(g);
        s += *(const floatx4*)(g + PS);
        s += *(const floatx4*)(g + 2 * PS);
        s += *(const floatx4*)(g + 3 * PS);
        *(floatx4*)&xsum[k][0] = s;
    }
    // phase 1b: vt[i_loc][f] (coalesced 1 KB)
    {
        const int il = tid >> 6, f = tid & 63;
        vt[il][f] = V[((size_t)(b * N_ + i0 + il)) * F_ + f];
    }
    // phase 1c: dsum[l][i_loc]
    if (tid < 16) {
        const int l = tid >> 2, il = tid & 3;
        float s = 0.0f;
#pragma unroll
        for (int p = 0; p < SK; ++p)
            s += degT[((size_t)((p * B_ + b) * L_ + l)) * N_ + i0 + il];
        dsum[l][il] = s;
    }
    __syncthreads();

    // phase 2: wave w -> f in [16w,16w+16), k in [64w,64w+64); lane = c.
    const int w = tid >> 6;
    const int c = tid & 63;

    // hoist deg into registers (LDS broadcast, static indices after unroll)
    float dl[4][4];
#pragma unroll
    for (int l = 0; l < 4; ++l)
#pragma unroll
        for (int il = 0; il < 4; ++il) dl[l][il] = dsum[l][il];

    float s0 = 0.0f, s1 = 0.0f, s2 = 0.0f, s3 = 0.0f;

    const int fbase = w * 16;
#pragma unroll 4
    for (int fi = 0; fi < 16; ++fi) {
        const int f = fbase + fi;
        const float W1  = w1[f * 64 + c];
        const float W20 = w2[(0 * 64 + f) * 64 + c];
        const float W21 = w2[(1 * 64 + f) * 64 + c];
        const float W22 = w2[(2 * 64 + f) * 64 + c];
        const float W23 = w2[(3 * 64 + f) * 64 + c];
        {
            float coef = W1 + dl[0][0] * W20 + dl[1][0] * W21 + dl[2][0] * W22 + dl[3][0] * W23;
            s0 += vt[0][f] * coef;
        }
        {
            float coef = W1 + dl[0][1] * W20 + dl[1][1] * W21 + dl[2][1] * W22 + dl[3][1] * W23;
            s1 += vt[1][f] * coef;
        }
        {
            float coef = W1 + dl[0][2] * W20 + dl[1][2] * W21 + dl[2][2] * W22 + dl[3][2] * W23;
            s2 += vt[2][f] * coef;
        }
        {
            float coef = W1 + dl[0][3] * W20 + dl[1][3] * W21 + dl[2][3] * W22 + dl[3][3] * W23;
            s3 += vt[3][f] * coef;
        }
    }

    const int kbase = w * 64;
#pragma unroll 4
    for (int ki = 0; ki < 64; ++ki) {
        const int k = kbase + ki;
        const float W3 = w3[k * 64 + c];
        const floatx4 xs = *(const floatx4*)&xsum[k][0];   // b128 broadcast
        s0 -= xs.x * W3;
        s1 -= xs.y * W3;
        s2 -= xs.z * W3;
        s3 -= xs.w * W3;
    }

    red[w][0][c] = s0;
    red[w][1][c] = s1;
    red[w][2][c] = s2;
    red[w][3][c] = s3;
    __syncthreads();

    // cross-wave reduce + sigmoid + store (wave = one i row, coalesced 256 B)
    {
        const int il = tid >> 6;
        const float acc = red[0][il][c] + red[1][il][c] + red[2][il][c] + red[3][il][c];
        out[((size_t)(b * N_ + i0 + il)) * C_ + c] = 1.0f / (1.0f + __expf(-acc));
    }
}

// ---------------------------------------------------------------------------
extern "C" void kernel_launch(void* const* d_in, const int* in_sizes, int n_in,
                              void* d_out, int out_size, void* d_ws, size_t ws_size,
                              hipStream_t stream) {
    const float* V  = (const float*)d_in[0];
    const float* A  = (const float*)d_in[1];
    const float* w1 = (const float*)d_in[2];
    const float* w2 = (const float*)d_in[3];
    const float* w3 = (const float*)d_in[4];
    float* out = (float*)d_out;

    char* ws = (char*)d_ws;
    float*    aggT = (float*)(ws);                  // SK*B*512*1024*4 = 16 MB (permuted layout)
    float*    degT = (float*)(ws + 16777216);       // SK*B*L*N*4   = 256 KB
    _Float16* Vth  = (_Float16*)(ws + 17039360);    // B*F*N*2      = 512 KB

    hipLaunchKernelGGL(k0_transpose, dim3(B_ * (N_ / 64)), dim3(256), 0, stream, V, Vth);
    hipLaunchKernelGGL(k1_agg,       dim3(B_ * (N_ / 16) * SK), dim3(256), 0, stream,
                       A, Vth, aggT, degT);
    hipLaunchKernelGGL(k2_out,       dim3(B_ * (N_ / 4)), dim3(256), 0, stream,
                       V, degT, aggT, w1, w2, w3, out);
}